// Round 2
// baseline (469.570 us; speedup 1.0000x reference)
//
#include <hip/hip_runtime.h>
#include <math.h>

#define N_NODES 100000
#define N_EDGES 1600000
#define D_IN 256
#define N_HEADS 4
#define D_OUT 32
#define D_HID 128   // N_HEADS*D_OUT
#define NEG_SLOPE 0.2f

#define NB ((N_NODES + 255) / 256)   // 391 scan blocks

typedef __attribute__((ext_vector_type(8))) short bf16x8;
typedef __attribute__((ext_vector_type(4))) float f32x4;

// hardware packed f32->bf16 (RNE), 1 inst per 2 elements
static __device__ __forceinline__ unsigned cvt2(float lo, float hi) {
  unsigned r;
  asm("v_cvt_pk_bf16_f32 %0, %1, %2" : "=v"(r) : "v"(lo), "v"(hi));
  return r;
}
static __device__ __forceinline__ float bfu_lo(unsigned u) {
  union { unsigned u; float f; } c; c.u = u << 16; return c.f;
}
static __device__ __forceinline__ float bfu_hi(unsigned u) {
  union { unsigned u; float f; } c; c.u = u & 0xFFFF0000u; return c.f;
}

// ---------------- GEMM: ftb[N,128](bf16) = x[N,256] @ w[128,256]^T ----------
#define LDA 40  // padded LDS row stride in bf16 elems
__global__ __launch_bounds__(256) void k_gemm(const float* __restrict__ x,
                                              const float* __restrict__ w,
                                              unsigned short* __restrict__ ftb) {
  __shared__ short As[128 * LDA];
  __shared__ short Bs[128 * LDA];
  int t = threadIdx.x;
  int wave = t >> 6, lane = t & 63;
  int quad = lane >> 4, l16 = lane & 15;
  int rowBase = blockIdx.x * 128;
  int wm = (wave >> 1) * 64, wn = (wave & 1) * 64;
  f32x4 acc[4][4];
  #pragma unroll
  for (int mt = 0; mt < 4; ++mt)
    #pragma unroll
    for (int nt = 0; nt < 4; ++nt) {
      acc[mt][nt][0] = 0.f; acc[mt][nt][1] = 0.f;
      acc[mt][nt][2] = 0.f; acc[mt][nt][3] = 0.f;
    }

  for (int kb = 0; kb < D_IN; kb += 32) {
    #pragma unroll
    for (int p = 0; p < 4; ++p) {
      int idx = p * 256 + t;
      int r = idx >> 3;
      int kq = (idx & 7) * 4;
      int row = rowBase + r;
      float4 v = make_float4(0.f, 0.f, 0.f, 0.f);
      if (row < N_NODES) v = *(const float4*)&x[(size_t)row * D_IN + kb + kq];
      unsigned* d = (unsigned*)&As[r * LDA + kq];
      d[0] = cvt2(v.x, v.y);
      d[1] = cvt2(v.z, v.w);
    }
    #pragma unroll
    for (int p = 0; p < 4; ++p) {
      int idx = p * 256 + t;
      int r = idx >> 3;
      int kq = (idx & 7) * 4;
      float4 v = *(const float4*)&w[(size_t)r * D_IN + kb + kq];
      unsigned* d = (unsigned*)&Bs[r * LDA + kq];
      d[0] = cvt2(v.x, v.y);
      d[1] = cvt2(v.z, v.w);
    }
    __syncthreads();
    bf16x8 af[4], bfr[4];
    #pragma unroll
    for (int mt = 0; mt < 4; ++mt)
      af[mt] = *(const bf16x8*)&As[(wm + mt * 16 + l16) * LDA + quad * 8];
    #pragma unroll
    for (int nt = 0; nt < 4; ++nt)
      bfr[nt] = *(const bf16x8*)&Bs[(wn + nt * 16 + l16) * LDA + quad * 8];
    #pragma unroll
    for (int mt = 0; mt < 4; ++mt)
      #pragma unroll
      for (int nt = 0; nt < 4; ++nt)
        acc[mt][nt] = __builtin_amdgcn_mfma_f32_16x16x32_bf16(af[mt], bfr[nt], acc[mt][nt], 0, 0, 0);
    __syncthreads();
  }
  #pragma unroll
  for (int mt = 0; mt < 4; ++mt) {
    #pragma unroll
    for (int nt = 0; nt < 4; ++nt) {
      int col = wn + nt * 16 + l16;
      #pragma unroll
      for (int r = 0; r < 4; r += 2) {
        unsigned p = cvt2(acc[mt][nt][r], acc[mt][nt][r + 1]);
        int row = rowBase + wm + mt * 16 + quad * 4 + r;
        if (row < N_NODES)
          ftb[(size_t)row * D_HID + col] = (unsigned short)p;
        if (row + 1 < N_NODES)
          ftb[(size_t)(row + 1) * D_HID + col] = (unsigned short)(p >> 16);
      }
    }
  }
}

// ---------------- per-node attention logits el,er [N,4] ----------------
__global__ void k_eler(const unsigned short* __restrict__ ftb,
                       const float* __restrict__ al,
                       const float* __restrict__ ar,
                       float* __restrict__ el, float* __restrict__ er) {
  int gid = blockIdx.x * blockDim.x + threadIdx.x;
  if (gid >= N_NODES * N_HEADS) return;
  int n = gid >> 2, h = gid & 3;
  const unsigned* f = (const unsigned*)&ftb[(size_t)n * D_HID + h * D_OUT];
  const float* alh = &al[h * D_OUT];
  const float* arh = &ar[h * D_OUT];
  float sl = 0.f, sr = 0.f;
  #pragma unroll
  for (int i = 0; i < 16; ++i) {
    unsigned u = f[i];
    float lo = bfu_lo(u), hi = bfu_hi(u);
    sl += lo * alh[2 * i] + hi * alh[2 * i + 1];
    sr += lo * arh[2 * i] + hi * arh[2 * i + 1];
  }
  el[gid] = sl;
  er[gid] = sr;
}

// ---------------- CSR build: count -> scan -> scatter ----------------------
__global__ __launch_bounds__(256) void k_count(const int* __restrict__ dst,
                                               int* __restrict__ cnt) {
  int i = blockIdx.x * 256 + threadIdx.x;
  if (i < N_EDGES) atomicAdd(&cnt[dst[i]], 1);
}

__global__ __launch_bounds__(256) void k_blocksum(const int* __restrict__ cnt,
                                                  int* __restrict__ bsum) {
  __shared__ int red[4];
  int b = blockIdx.x, t = threadIdx.x;
  int node = b * 256 + t;
  int v = (node < N_NODES) ? cnt[node] : 0;
  #pragma unroll
  for (int o = 32; o > 0; o >>= 1) v += __shfl_xor(v, o);
  if ((t & 63) == 0) red[t >> 6] = v;
  __syncthreads();
  if (t == 0) bsum[b] = red[0] + red[1] + red[2] + red[3];
}

// exclusive scan of 391 block sums -> bbase; also offs[N]=E
__global__ __launch_bounds__(512) void k_scanbuckets(const int* __restrict__ bsum,
                                                     int* __restrict__ bbase,
                                                     int* __restrict__ offs) {
  __shared__ int ss[512];
  int t = threadIdx.x;
  int v = (t < NB) ? bsum[t] : 0;
  ss[t] = v;
  __syncthreads();
  #pragma unroll
  for (int d = 1; d < 512; d <<= 1) {
    int u = (t >= d) ? ss[t - d] : 0;
    __syncthreads();
    ss[t] += u;
    __syncthreads();
  }
  if (t < NB) bbase[t] = (t == 0) ? 0 : ss[t - 1];
  if (t == 0) offs[N_NODES] = N_EDGES;
}

__global__ __launch_bounds__(256) void k_scanwrite(const int* __restrict__ cnt,
                                                   const int* __restrict__ bbase,
                                                   int* __restrict__ offs,
                                                   int* __restrict__ cur) {
  __shared__ int ss[256];
  int b = blockIdx.x, t = threadIdx.x;
  int node = b * 256 + t;
  int v = (node < N_NODES) ? cnt[node] : 0;
  ss[t] = v;
  __syncthreads();
  #pragma unroll
  for (int d = 1; d < 256; d <<= 1) {
    int u = (t >= d) ? ss[t - d] : 0;
    __syncthreads();
    ss[t] += u;
    __syncthreads();
  }
  if (node < N_NODES) {
    int o = bbase[b] + ss[t] - v;   // exclusive
    offs[node] = o;
    cur[node] = o;
  }
}

__global__ __launch_bounds__(256) void k_scatter(const int* __restrict__ src,
                                                 const int* __restrict__ dst,
                                                 int* __restrict__ cur,
                                                 int* __restrict__ ssrc) {
  int i = blockIdx.x * 256 + threadIdx.x;
  if (i < N_EDGES) {
    int pos = atomicAdd(&cur[dst[i]], 1);
    ssrc[pos] = src[i];
  }
}

// ---------------- per-node softmax + weighted aggregation (bf16 ft) --------
__global__ __launch_bounds__(256) void k_agg(const int* __restrict__ offs,
                                             const int* __restrict__ ssrc,
                                             const unsigned short* __restrict__ ftb,
                                             const float* __restrict__ el,
                                             const float* __restrict__ er,
                                             float* __restrict__ out) {
  __shared__ int   lds_s[4][64];
  __shared__ float lds_ah[4][4][64];   // [wave][head][edge] transposed
  int wave = threadIdx.x >> 6;
  int lane = threadIdx.x & 63;
  int n = blockIdx.x * 4 + wave;
  if (n >= N_NODES) return;
  int start = offs[n], end = offs[n + 1];
  int deg = end - start;

  if (deg <= 64) {
    // ---- softmax: lane = edge ----
    float4 er4 = *(const float4*)&er[n * 4];
    bool valid = lane < deg;
    int s = valid ? ssrc[start + lane] : 0;
    float4 e4 = *(const float4*)&el[s * 4];
    float v[4] = {e4.x + er4.x, e4.y + er4.y, e4.z + er4.z, e4.w + er4.w};
    float m[4], ex[4], den[4];
    #pragma unroll
    for (int h = 0; h < 4; ++h) {
      v[h] = v[h] > 0.f ? v[h] : NEG_SLOPE * v[h];
      m[h] = valid ? v[h] : -INFINITY;
    }
    #pragma unroll
    for (int h = 0; h < 4; ++h)
      #pragma unroll
      for (int o = 32; o > 0; o >>= 1) m[h] = fmaxf(m[h], __shfl_xor(m[h], o));
    #pragma unroll
    for (int h = 0; h < 4; ++h) {
      ex[h] = valid ? __expf(v[h] - m[h]) : 0.f;
      den[h] = ex[h];
    }
    #pragma unroll
    for (int h = 0; h < 4; ++h)
      #pragma unroll
      for (int o = 32; o > 0; o >>= 1) den[h] += __shfl_xor(den[h], o);
    lds_s[wave][lane] = s;
    #pragma unroll
    for (int h = 0; h < 4; ++h)
      lds_ah[wave][h][lane] = ex[h] / den[h];
    __builtin_amdgcn_wave_barrier();

    // ---- aggregation: lane covers cols (2*lane, 2*lane+1); 4 edges/iter ----
    int f0 = lane * 2;
    int hh = lane >> 4;
    const unsigned short* fb = ftb + f0;
    float2 acc0 = {0.f, 0.f}, acc1 = {0.f, 0.f};
    float2 acc2 = {0.f, 0.f}, acc3 = {0.f, 0.f};
    int j = 0;
    for (; j + 4 <= deg; j += 4) {
      int4   sv = *(const int4*)&lds_s[wave][j];
      float4 av = *(const float4*)&lds_ah[wave][hh][j];
      unsigned u0 = *(const unsigned*)&fb[(size_t)sv.x * D_HID];
      unsigned u1 = *(const unsigned*)&fb[(size_t)sv.y * D_HID];
      unsigned u2 = *(const unsigned*)&fb[(size_t)sv.z * D_HID];
      unsigned u3 = *(const unsigned*)&fb[(size_t)sv.w * D_HID];
      acc0.x += av.x * bfu_lo(u0); acc0.y += av.x * bfu_hi(u0);
      acc1.x += av.y * bfu_lo(u1); acc1.y += av.y * bfu_hi(u1);
      acc2.x += av.z * bfu_lo(u2); acc2.y += av.z * bfu_hi(u2);
      acc3.x += av.w * bfu_lo(u3); acc3.y += av.w * bfu_hi(u3);
    }
    for (; j < deg; ++j) {
      int sj = lds_s[wave][j];
      float a = lds_ah[wave][hh][j];
      unsigned u = *(const unsigned*)&fb[(size_t)sj * D_HID];
      acc0.x += a * bfu_lo(u); acc0.y += a * bfu_hi(u);
    }
    float2 acc;
    acc.x = (acc0.x + acc1.x) + (acc2.x + acc3.x);
    acc.y = (acc0.y + acc1.y) + (acc2.y + acc3.y);
    *(float2*)&out[(size_t)n * D_HID + f0] = acc;
  } else {
    // ---- rare high-degree path (deg > 64) ----
    int f0 = lane * 2;
    int hh = lane >> 4;
    float2 acc = {0.f, 0.f};
    float4 er4 = *(const float4*)&er[n * 4];
    float erh[4] = {er4.x, er4.y, er4.z, er4.w};
    float m[4] = {-INFINITY, -INFINITY, -INFINITY, -INFINITY};
    for (int c = start; c < end; c += 64) {
      int i = c + lane;
      bool valid = i < end;
      int s = valid ? ssrc[i] : 0;
      float4 e4 = *(const float4*)&el[s * 4];
      float ee[4] = {e4.x, e4.y, e4.z, e4.w};
      #pragma unroll
      for (int h = 0; h < 4; ++h) {
        float v = ee[h] + erh[h];
        v = v > 0.f ? v : NEG_SLOPE * v;
        if (!valid) v = -INFINITY;
        m[h] = fmaxf(m[h], v);
      }
    }
    #pragma unroll
    for (int h = 0; h < 4; ++h)
      #pragma unroll
      for (int o = 32; o > 0; o >>= 1) m[h] = fmaxf(m[h], __shfl_xor(m[h], o));
    float den[4] = {0.f, 0.f, 0.f, 0.f};
    for (int c = start; c < end; c += 64) {
      int i = c + lane;
      bool valid = i < end;
      int s = valid ? ssrc[i] : 0;
      float4 e4 = *(const float4*)&el[s * 4];
      float ee[4] = {e4.x, e4.y, e4.z, e4.w};
      #pragma unroll
      for (int h = 0; h < 4; ++h) {
        float v = ee[h] + erh[h];
        v = v > 0.f ? v : NEG_SLOPE * v;
        den[h] += valid ? __expf(v - m[h]) : 0.f;
      }
    }
    #pragma unroll
    for (int h = 0; h < 4; ++h)
      #pragma unroll
      for (int o = 32; o > 0; o >>= 1) den[h] += __shfl_xor(den[h], o);
    float invd = 1.f / den[hh];
    for (int c = start; c < end; c += 64) {
      int i = c + lane;
      bool valid = i < end;
      int s = valid ? ssrc[i] : 0;
      float4 e4 = *(const float4*)&el[s * 4];
      float ee[4] = {e4.x, e4.y, e4.z, e4.w};
      float ex[4];
      #pragma unroll
      for (int h = 0; h < 4; ++h) {
        float v = ee[h] + erh[h];
        v = v > 0.f ? v : NEG_SLOPE * v;
        ex[h] = __expf(v - m[h]);
      }
      int cnt2 = min(64, end - c);
      for (int j = 0; j < cnt2; ++j) {
        int sj = __shfl(s, j);
        float a0 = __shfl(ex[0], j);
        float a1 = __shfl(ex[1], j);
        float a2 = __shfl(ex[2], j);
        float a3 = __shfl(ex[3], j);
        float ah = hh == 0 ? a0 : (hh == 1 ? a1 : (hh == 2 ? a2 : a3));
        ah *= invd;
        unsigned u = *(const unsigned*)&ftb[(size_t)sj * D_HID + f0];
        acc.x += ah * bfu_lo(u);
        acc.y += ah * bfu_hi(u);
      }
    }
    *(float2*)&out[(size_t)n * D_HID + f0] = acc;
  }
}

extern "C" void kernel_launch(void* const* d_in, const int* in_sizes, int n_in,
                              void* d_out, int out_size, void* d_ws, size_t ws_size,
                              hipStream_t stream) {
  const float* x      = (const float*)d_in[0];
  const float* fc_w   = (const float*)d_in[1];
  const float* attn_l = (const float*)d_in[2];
  const float* attn_r = (const float*)d_in[3];
  const int*   src    = (const int*)d_in[4];
  const int*   dst    = (const int*)d_in[5];
  float* out = (float*)d_out;

  char* wsp = (char*)d_ws;
  size_t off = 0;
  auto alloc = [&](size_t bytes) {
    void* p = wsp + off;
    off = (off + bytes + 255) & ~(size_t)255;
    return p;
  };
  unsigned short* ftb = (unsigned short*)alloc((size_t)N_NODES * D_HID * 2);
  float* el     = (float*)alloc((size_t)N_NODES * 4 * 4);
  float* er     = (float*)alloc((size_t)N_NODES * 4 * 4);
  int*   offs   = (int*)alloc((size_t)(N_NODES + 1) * 4);
  int*   ssrc   = (int*)alloc((size_t)N_EDGES * 4);
  int*   cnt    = (int*)alloc((size_t)N_NODES * 4);
  int*   cur    = (int*)alloc((size_t)N_NODES * 4);
  int*   bsum   = (int*)alloc((size_t)NB * 4);
  int*   bbase  = (int*)alloc((size_t)NB * 4);

  hipMemsetAsync(cnt, 0, (size_t)N_NODES * 4, stream);
  k_gemm<<<(N_NODES + 127) / 128, 256, 0, stream>>>(x, fc_w, ftb);
  k_eler<<<(N_NODES * N_HEADS + 255) / 256, 256, 0, stream>>>(ftb, attn_l, attn_r, el, er);
  k_count<<<(N_EDGES + 255) / 256, 256, 0, stream>>>(dst, cnt);
  k_blocksum<<<NB, 256, 0, stream>>>(cnt, bsum);
  k_scanbuckets<<<1, 512, 0, stream>>>(bsum, bbase, offs);
  k_scanwrite<<<NB, 256, 0, stream>>>(cnt, bbase, offs, cur);
  k_scatter<<<(N_EDGES + 255) / 256, 256, 0, stream>>>(src, dst, cur, ssrc);
  k_agg<<<(N_NODES + 3) / 4, 256, 0, stream>>>(offs, ssrc, ftb, el, er, out);
}

// Round 3
// 324.692 us; speedup vs baseline: 1.4462x; 1.4462x over previous
//
#include <hip/hip_runtime.h>
#include <math.h>

#define N_NODES 100000
#define N_EDGES 1600000
#define D_IN 256
#define N_HEADS 4
#define D_OUT 32
#define D_HID 128   // N_HEADS*D_OUT
#define NEG_SLOPE 0.2f

// bucketed sort params
#define BUCKET_SHIFT 8
#define BUCKET_NODES 256
#define NB ((N_NODES + BUCKET_NODES - 1) / BUCKET_NODES)  // 391
#define CAP 6144      // >> mean 4096 + 32 sigma
#define TILE 2048
#define EPT 8         // edges per thread in k_bucket
#define N_TILES ((N_EDGES + TILE - 1) / TILE)             // 782

typedef __attribute__((ext_vector_type(8))) short bf16x8;
typedef __attribute__((ext_vector_type(4))) float f32x4;

// hardware packed f32->bf16 (RNE), 1 inst per 2 elements
static __device__ __forceinline__ unsigned cvt2(float lo, float hi) {
  unsigned r;
  asm("v_cvt_pk_bf16_f32 %0, %1, %2" : "=v"(r) : "v"(lo), "v"(hi));
  return r;
}
static __device__ __forceinline__ float bfu_lo(unsigned u) {
  union { unsigned u; float f; } c; c.u = u << 16; return c.f;
}
static __device__ __forceinline__ float bfu_hi(unsigned u) {
  union { unsigned u; float f; } c; c.u = u & 0xFFFF0000u; return c.f;
}

// ---------------- GEMM: ftb[N,128](bf16) = x[N,256] @ w[128,256]^T ----------
#define LDA 40  // padded LDS row stride in bf16 elems
__global__ __launch_bounds__(256) void k_gemm(const float* __restrict__ x,
                                              const float* __restrict__ w,
                                              unsigned short* __restrict__ ftb) {
  __shared__ short As[128 * LDA];
  __shared__ short Bs[128 * LDA];
  int t = threadIdx.x;
  int wave = t >> 6, lane = t & 63;
  int quad = lane >> 4, l16 = lane & 15;
  int rowBase = blockIdx.x * 128;
  int wm = (wave >> 1) * 64, wn = (wave & 1) * 64;
  f32x4 acc[4][4];
  #pragma unroll
  for (int mt = 0; mt < 4; ++mt)
    #pragma unroll
    for (int nt = 0; nt < 4; ++nt) {
      acc[mt][nt][0] = 0.f; acc[mt][nt][1] = 0.f;
      acc[mt][nt][2] = 0.f; acc[mt][nt][3] = 0.f;
    }

  for (int kb = 0; kb < D_IN; kb += 32) {
    #pragma unroll
    for (int p = 0; p < 4; ++p) {
      int idx = p * 256 + t;
      int r = idx >> 3;
      int kq = (idx & 7) * 4;
      int row = rowBase + r;
      float4 v = make_float4(0.f, 0.f, 0.f, 0.f);
      if (row < N_NODES) v = *(const float4*)&x[(size_t)row * D_IN + kb + kq];
      unsigned* d = (unsigned*)&As[r * LDA + kq];
      d[0] = cvt2(v.x, v.y);
      d[1] = cvt2(v.z, v.w);
    }
    #pragma unroll
    for (int p = 0; p < 4; ++p) {
      int idx = p * 256 + t;
      int r = idx >> 3;
      int kq = (idx & 7) * 4;
      float4 v = *(const float4*)&w[(size_t)r * D_IN + kb + kq];
      unsigned* d = (unsigned*)&Bs[r * LDA + kq];
      d[0] = cvt2(v.x, v.y);
      d[1] = cvt2(v.z, v.w);
    }
    __syncthreads();
    bf16x8 af[4], bfr[4];
    #pragma unroll
    for (int mt = 0; mt < 4; ++mt)
      af[mt] = *(const bf16x8*)&As[(wm + mt * 16 + l16) * LDA + quad * 8];
    #pragma unroll
    for (int nt = 0; nt < 4; ++nt)
      bfr[nt] = *(const bf16x8*)&Bs[(wn + nt * 16 + l16) * LDA + quad * 8];
    #pragma unroll
    for (int mt = 0; mt < 4; ++mt)
      #pragma unroll
      for (int nt = 0; nt < 4; ++nt)
        acc[mt][nt] = __builtin_amdgcn_mfma_f32_16x16x32_bf16(af[mt], bfr[nt], acc[mt][nt], 0, 0, 0);
    __syncthreads();
  }
  #pragma unroll
  for (int mt = 0; mt < 4; ++mt) {
    #pragma unroll
    for (int nt = 0; nt < 4; ++nt) {
      int col = wn + nt * 16 + l16;
      #pragma unroll
      for (int r = 0; r < 4; r += 2) {
        unsigned p = cvt2(acc[mt][nt][r], acc[mt][nt][r + 1]);
        int row = rowBase + wm + mt * 16 + quad * 4 + r;
        if (row < N_NODES)
          ftb[(size_t)row * D_HID + col] = (unsigned short)p;
        if (row + 1 < N_NODES)
          ftb[(size_t)(row + 1) * D_HID + col] = (unsigned short)(p >> 16);
      }
    }
  }
}

// ---------------- per-node attention logits el,er [N,4] ----------------
__global__ void k_eler(const unsigned short* __restrict__ ftb,
                       const float* __restrict__ al,
                       const float* __restrict__ ar,
                       float* __restrict__ el, float* __restrict__ er) {
  int gid = blockIdx.x * blockDim.x + threadIdx.x;
  if (gid >= N_NODES * N_HEADS) return;
  int n = gid >> 2, h = gid & 3;
  const unsigned* f = (const unsigned*)&ftb[(size_t)n * D_HID + h * D_OUT];
  const float* alh = &al[h * D_OUT];
  const float* arh = &ar[h * D_OUT];
  float sl = 0.f, sr = 0.f;
  #pragma unroll
  for (int i = 0; i < 16; ++i) {
    unsigned u = f[i];
    float lo = bfu_lo(u), hi = bfu_hi(u);
    sl += lo * alh[2 * i] + hi * alh[2 * i + 1];
    sr += lo * arh[2 * i] + hi * arh[2 * i + 1];
  }
  el[gid] = sl;
  er[gid] = sr;
}

// ---------------- phase 1: bucket edges by dst>>8, packed (src<<8)|dlocal ---
// Edges register-cached: each thread owns EPT contiguous edges (one int4x2
// load per array), so src/dst are read exactly once from HBM.
__global__ __launch_bounds__(256) void k_bucket(const int* __restrict__ src,
                                                const int* __restrict__ dst,
                                                int* __restrict__ gfill,
                                                unsigned* __restrict__ pairs) {
  __shared__ int bcnt[NB];
  __shared__ int brsv[NB];
  __shared__ int brank[NB];
  int t = threadIdx.x;
  for (int tile = blockIdx.x; tile < N_TILES; tile += gridDim.x) {
    int e0 = tile * TILE + t * EPT;
    for (int i = t; i < NB; i += 256) { bcnt[i] = 0; brank[i] = 0; }
    __syncthreads();
    int ds[EPT], ss[EPT];
    if (e0 + EPT <= N_EDGES) {
      *(int4*)&ds[0] = *(const int4*)&dst[e0];
      *(int4*)&ds[4] = *(const int4*)&dst[e0 + 4];
      *(int4*)&ss[0] = *(const int4*)&src[e0];
      *(int4*)&ss[4] = *(const int4*)&src[e0 + 4];
    } else {
      #pragma unroll
      for (int k = 0; k < EPT; ++k) {
        int e = e0 + k;
        ds[k] = (e < N_EDGES) ? dst[e] : -1;
        ss[k] = (e < N_EDGES) ? src[e] : 0;
      }
    }
    #pragma unroll
    for (int k = 0; k < EPT; ++k)
      if (ds[k] >= 0) atomicAdd(&bcnt[ds[k] >> BUCKET_SHIFT], 1);
    __syncthreads();
    for (int i = t; i < NB; i += 256) {
      int c = bcnt[i];
      brsv[i] = (c > 0) ? atomicAdd(&gfill[i], c) : 0;
    }
    __syncthreads();
    #pragma unroll
    for (int k = 0; k < EPT; ++k) {
      if (ds[k] >= 0) {
        int b = ds[k] >> BUCKET_SHIFT;
        int r = brsv[b] + atomicAdd(&brank[b], 1);
        if (r < CAP)
          pairs[(size_t)b * CAP + r] =
              ((unsigned)ss[k] << 8) | (unsigned)(ds[k] & (BUCKET_NODES - 1));
      }
    }
    __syncthreads();
  }
}

// ---------------- phase 2: exclusive scan of bucket fills -------------------
__global__ __launch_bounds__(512) void k_scanbuckets(const int* __restrict__ gfill,
                                                     int* __restrict__ bbase,
                                                     int* __restrict__ offs) {
  __shared__ int ss[512];
  int t = threadIdx.x;
  int v = (t < NB) ? gfill[t] : 0;
  ss[t] = v;
  __syncthreads();
  #pragma unroll
  for (int d = 1; d < 512; d <<= 1) {
    int u = (t >= d) ? ss[t - d] : 0;
    __syncthreads();
    ss[t] += u;
    __syncthreads();
  }
  if (t < NB) bbase[t] = (t == 0) ? 0 : ss[t - 1];
  if (t == 0) offs[N_NODES] = N_EDGES;
}

// ---------------- phase 3: per-bucket counting sort -> offs, ssrc -----------
__global__ __launch_bounds__(512) void k_localsort(const unsigned* __restrict__ pairs,
                                                   const int* __restrict__ gfill,
                                                   const int* __restrict__ bbase,
                                                   int* __restrict__ offs,
                                                   int* __restrict__ ssrc) {
  __shared__ int cnt_l[256];
  __shared__ int ss[256];
  __shared__ int cur_l[256];
  int b = blockIdx.x, t = threadIdx.x;
  int E = min(gfill[b], CAP);
  int base = bbase[b];
  const unsigned* pb = &pairs[(size_t)b * CAP];
  if (t < 256) cnt_l[t] = 0;
  __syncthreads();
  for (int i = t; i < E; i += 512)
    atomicAdd(&cnt_l[pb[i] & (BUCKET_NODES - 1)], 1);
  __syncthreads();
  if (t < 256) ss[t] = cnt_l[t];
  __syncthreads();
  #pragma unroll
  for (int d = 1; d < 256; d <<= 1) {
    int u = (t < 256 && t >= d) ? ss[t - d] : 0;
    __syncthreads();
    if (t < 256) ss[t] += u;
    __syncthreads();
  }
  if (t < 256) {
    int pre = (t == 0) ? 0 : ss[t - 1];
    int node = b * BUCKET_NODES + t;
    if (node < N_NODES) offs[node] = base + pre;
    cur_l[t] = pre;
  }
  __syncthreads();
  for (int i = t; i < E; i += 512) {
    unsigned p = pb[i];
    int pos = atomicAdd(&cur_l[p & (BUCKET_NODES - 1)], 1);
    ssrc[base + pos] = (int)(p >> 8);
  }
}

// ---------------- per-node softmax + weighted aggregation (bf16 ft) --------
#define AHP 72   // padded edge-dim: 16B-aligned (72*4=288) and bank-spread
__global__ __launch_bounds__(256) void k_agg(const int* __restrict__ offs,
                                             const int* __restrict__ ssrc,
                                             const unsigned short* __restrict__ ftb,
                                             const float* __restrict__ el,
                                             const float* __restrict__ er,
                                             float* __restrict__ out) {
  __shared__ int   lds_s[4][64];
  __shared__ float lds_ah[4][4][AHP];   // [wave][head][edge]
  int wave = threadIdx.x >> 6;
  int lane = threadIdx.x & 63;
  int n = blockIdx.x * 4 + wave;
  if (n >= N_NODES) return;
  int start = offs[n], end = offs[n + 1];
  int deg = end - start;

  if (deg <= 64) {
    // ---- softmax: lane = edge ----
    float4 er4 = *(const float4*)&er[n * 4];
    bool valid = lane < deg;
    int s = valid ? ssrc[start + lane] : 0;
    float4 e4 = *(const float4*)&el[s * 4];
    float v[4] = {e4.x + er4.x, e4.y + er4.y, e4.z + er4.z, e4.w + er4.w};
    float m[4], ex[4], den[4];
    #pragma unroll
    for (int h = 0; h < 4; ++h) {
      v[h] = v[h] > 0.f ? v[h] : NEG_SLOPE * v[h];
      m[h] = valid ? v[h] : -INFINITY;
    }
    #pragma unroll
    for (int h = 0; h < 4; ++h)
      #pragma unroll
      for (int o = 32; o > 0; o >>= 1) m[h] = fmaxf(m[h], __shfl_xor(m[h], o));
    #pragma unroll
    for (int h = 0; h < 4; ++h) {
      ex[h] = valid ? __expf(v[h] - m[h]) : 0.f;
      den[h] = ex[h];
    }
    #pragma unroll
    for (int h = 0; h < 4; ++h)
      #pragma unroll
      for (int o = 32; o > 0; o >>= 1) den[h] += __shfl_xor(den[h], o);
    lds_s[wave][lane] = s;
    #pragma unroll
    for (int h = 0; h < 4; ++h)
      lds_ah[wave][h][lane] = ex[h] / den[h];
    __builtin_amdgcn_wave_barrier();

    // ---- aggregation: 32 lanes x 4 cols; wave halves = 2 edge slots ----
    int epar = lane >> 5;          // edge parity slot
    int c4 = (lane & 31) * 4;      // column base (4 bf16 cols per lane)
    int hh = c4 >> 5;              // head of this column group
    const unsigned short* fb = ftb + c4;
    float acc[4] = {0.f, 0.f, 0.f, 0.f};
    for (int j = 0; j < deg; j += 8) {
      int4   sv0 = *(const int4*)&lds_s[wave][j];
      int4   sv1 = *(const int4*)&lds_s[wave][j + 4];
      float4 av0 = *(const float4*)&lds_ah[wave][hh][j];
      float4 av1 = *(const float4*)&lds_ah[wave][hh][j + 4];
      int   sA = epar ? sv0.y : sv0.x;  float aA = epar ? av0.y : av0.x;
      int   sB = epar ? sv0.w : sv0.z;  float aB = epar ? av0.w : av0.z;
      int   sC = epar ? sv1.y : sv1.x;  float aC = epar ? av1.y : av1.x;
      int   sD = epar ? sv1.w : sv1.z;  float aD = epar ? av1.w : av1.z;
      uint2 uA = *(const uint2*)&fb[(size_t)sA * D_HID];
      uint2 uB = *(const uint2*)&fb[(size_t)sB * D_HID];
      uint2 uC = *(const uint2*)&fb[(size_t)sC * D_HID];
      uint2 uD = *(const uint2*)&fb[(size_t)sD * D_HID];
      acc[0] += aA * bfu_lo(uA.x); acc[1] += aA * bfu_hi(uA.x);
      acc[2] += aA * bfu_lo(uA.y); acc[3] += aA * bfu_hi(uA.y);
      acc[0] += aB * bfu_lo(uB.x); acc[1] += aB * bfu_hi(uB.x);
      acc[2] += aB * bfu_lo(uB.y); acc[3] += aB * bfu_hi(uB.y);
      acc[0] += aC * bfu_lo(uC.x); acc[1] += aC * bfu_hi(uC.x);
      acc[2] += aC * bfu_lo(uC.y); acc[3] += aC * bfu_hi(uC.y);
      acc[0] += aD * bfu_lo(uD.x); acc[1] += aD * bfu_hi(uD.x);
      acc[2] += aD * bfu_lo(uD.y); acc[3] += aD * bfu_hi(uD.y);
    }
    #pragma unroll
    for (int i = 0; i < 4; ++i) acc[i] += __shfl_xor(acc[i], 32);
    if (epar == 0)
      *(float4*)&out[(size_t)n * D_HID + c4] =
          make_float4(acc[0], acc[1], acc[2], acc[3]);
  } else {
    // ---- rare high-degree path (deg > 64) ----
    int f0 = lane * 2;
    int hh = lane >> 4;
    float2 acc = {0.f, 0.f};
    float4 er4 = *(const float4*)&er[n * 4];
    float erh[4] = {er4.x, er4.y, er4.z, er4.w};
    float m[4] = {-INFINITY, -INFINITY, -INFINITY, -INFINITY};
    for (int c = start; c < end; c += 64) {
      int i = c + lane;
      bool valid = i < end;
      int s = valid ? ssrc[i] : 0;
      float4 e4 = *(const float4*)&el[s * 4];
      float ee[4] = {e4.x, e4.y, e4.z, e4.w};
      #pragma unroll
      for (int h = 0; h < 4; ++h) {
        float v = ee[h] + erh[h];
        v = v > 0.f ? v : NEG_SLOPE * v;
        if (!valid) v = -INFINITY;
        m[h] = fmaxf(m[h], v);
      }
    }
    #pragma unroll
    for (int h = 0; h < 4; ++h)
      #pragma unroll
      for (int o = 32; o > 0; o >>= 1) m[h] = fmaxf(m[h], __shfl_xor(m[h], o));
    float den[4] = {0.f, 0.f, 0.f, 0.f};
    for (int c = start; c < end; c += 64) {
      int i = c + lane;
      bool valid = i < end;
      int s = valid ? ssrc[i] : 0;
      float4 e4 = *(const float4*)&el[s * 4];
      float ee[4] = {e4.x, e4.y, e4.z, e4.w};
      #pragma unroll
      for (int h = 0; h < 4; ++h) {
        float v = ee[h] + erh[h];
        v = v > 0.f ? v : NEG_SLOPE * v;
        den[h] += valid ? __expf(v - m[h]) : 0.f;
      }
    }
    #pragma unroll
    for (int h = 0; h < 4; ++h)
      #pragma unroll
      for (int o = 32; o > 0; o >>= 1) den[h] += __shfl_xor(den[h], o);
    float invd = 1.f / den[hh];
    for (int c = start; c < end; c += 64) {
      int i = c + lane;
      bool valid = i < end;
      int s = valid ? ssrc[i] : 0;
      float4 e4 = *(const float4*)&el[s * 4];
      float ee[4] = {e4.x, e4.y, e4.z, e4.w};
      float ex[4];
      #pragma unroll
      for (int h = 0; h < 4; ++h) {
        float v = ee[h] + erh[h];
        v = v > 0.f ? v : NEG_SLOPE * v;
        ex[h] = __expf(v - m[h]);
      }
      int cnt2 = min(64, end - c);
      for (int j = 0; j < cnt2; ++j) {
        int sj = __shfl(s, j);
        float a0 = __shfl(ex[0], j);
        float a1 = __shfl(ex[1], j);
        float a2 = __shfl(ex[2], j);
        float a3 = __shfl(ex[3], j);
        float ah = hh == 0 ? a0 : (hh == 1 ? a1 : (hh == 2 ? a2 : a3));
        ah *= invd;
        unsigned u = *(const unsigned*)&ftb[(size_t)sj * D_HID + f0];
        acc.x += ah * bfu_lo(u);
        acc.y += ah * bfu_hi(u);
      }
    }
    *(float2*)&out[(size_t)n * D_HID + f0] = acc;
  }
}

extern "C" void kernel_launch(void* const* d_in, const int* in_sizes, int n_in,
                              void* d_out, int out_size, void* d_ws, size_t ws_size,
                              hipStream_t stream) {
  const float* x      = (const float*)d_in[0];
  const float* fc_w   = (const float*)d_in[1];
  const float* attn_l = (const float*)d_in[2];
  const float* attn_r = (const float*)d_in[3];
  const int*   src    = (const int*)d_in[4];
  const int*   dst    = (const int*)d_in[5];
  float* out = (float*)d_out;

  char* wsp = (char*)d_ws;
  size_t off = 0;
  auto alloc = [&](size_t bytes) {
    void* p = wsp + off;
    off = (off + bytes + 255) & ~(size_t)255;
    return p;
  };
  unsigned short* ftb = (unsigned short*)alloc((size_t)N_NODES * D_HID * 2);
  float* el     = (float*)alloc((size_t)N_NODES * 4 * 4);
  float* er     = (float*)alloc((size_t)N_NODES * 4 * 4);
  int*   offs   = (int*)alloc((size_t)(N_NODES + 1) * 4);
  int*   ssrc   = (int*)alloc((size_t)N_EDGES * 4);
  int*   gfill  = (int*)alloc((size_t)NB * 4);
  int*   bbase  = (int*)alloc((size_t)NB * 4);
  unsigned* pairs = (unsigned*)alloc((size_t)NB * CAP * 4);

  hipMemsetAsync(gfill, 0, (size_t)NB * 4, stream);
  k_gemm<<<(N_NODES + 127) / 128, 256, 0, stream>>>(x, fc_w, ftb);
  k_eler<<<(N_NODES * N_HEADS + 255) / 256, 256, 0, stream>>>(ftb, attn_l, attn_r, el, er);
  k_bucket<<<N_TILES, 256, 0, stream>>>(src, dst, gfill, pairs);
  k_scanbuckets<<<1, 512, 0, stream>>>(gfill, bbase, offs);
  k_localsort<<<NB, 512, 0, stream>>>(pairs, gfill, bbase, offs, ssrc);
  k_agg<<<(N_NODES + 3) / 4, 256, 0, stream>>>(offs, ssrc, ftb, el, er, out);
}